// Round 4
// baseline (1207.990 us; speedup 1.0000x reference)
//
#include <hip/hip_runtime.h>
#include <hip/hip_bf16.h>
#include <math.h>

#define BB 64
#define LL 384
#define DD 128
#define HH 8
#define DHH 16
#define DEPTH 6
#define FFD 512
#define MROWS (BB*LL)      // 24576
#define COUT 128
#define KP (LL*DD)         // 49152

typedef short bf16x8 __attribute__((ext_vector_type(8)));
typedef float f32x4 __attribute__((ext_vector_type(4)));

// ---------------- embed + axial pos ----------------
__global__ __launch_bounds__(256) void embed_kernel(
    const int* __restrict__ x_enc, const float* __restrict__ emb,
    const float* __restrict__ pos1, const float* __restrict__ pos2,
    float* __restrict__ x1, float* __restrict__ x2)
{
    int t = blockIdx.x * 256 + threadIdx.x;      // over MROWS * 32 float4
    int row = t >> 5;
    int c4 = t & 31;
    int l = row % LL;
    int tok = x_enc[row];
    float4 a = ((const float4*)(emb + (size_t)tok * DD))[c4];
    float4 b = ((const float4*)(pos1 + (l / 25) * DD))[c4];
    float4 c = ((const float4*)(pos2 + (l % 25) * DD))[c4];
    float4 r = make_float4(a.x + b.x + c.x, a.y + b.y + c.y,
                           a.z + b.z + c.z, a.w + b.w + c.w);
    ((float4*)x1)[t] = r;
    ((float4*)x2)[t] = r;
}

// ---------------- weight cast + transpose: W[K,N] fp32 -> Wt[N,K] bf16 ----------------
__global__ __launch_bounds__(256) void castT_kernel(
    const float* __restrict__ src, __hip_bfloat16* __restrict__ dst, int K, int N,
    long sstride, long dstride)
{
    __shared__ float tile[32][33];
    int kb = blockIdx.x * 32, nb = blockIdx.y * 32;
    int tx = threadIdx.x & 31, ty = threadIdx.x >> 5;   // ty 0..7
    const float* s = src + (size_t)blockIdx.z * sstride;
    __hip_bfloat16* d = dst + (size_t)blockIdx.z * dstride;
    #pragma unroll
    for (int r = 0; r < 32; r += 8)
        tile[r + ty][tx] = s[(size_t)(kb + r + ty) * N + nb + tx];
    __syncthreads();
    #pragma unroll
    for (int r = 0; r < 32; r += 8)
        d[(size_t)(nb + r + ty) * K + kb + tx] = __float2bfloat16(tile[tx][r + ty]);
}

// ---------------- LayerNorm (wave per row) -> bf16 out ----------------
__global__ __launch_bounds__(256) void ln_kernel(
    const float* __restrict__ x, const float* __restrict__ g,
    const float* __restrict__ b, __hip_bfloat16* __restrict__ y)
{
    int wave = threadIdx.x >> 6;
    int lane = threadIdx.x & 63;
    int row = blockIdx.x * 4 + wave;
    float2 v = ((const float2*)(x + (size_t)row * DD))[lane];
    float2 gg = ((const float2*)g)[lane];
    float2 bb = ((const float2*)b)[lane];
    float s = v.x + v.y;
    float sq = v.x * v.x + v.y * v.y;
    #pragma unroll
    for (int off = 32; off > 0; off >>= 1) {
        s += __shfl_down(s, off, 64);
        sq += __shfl_down(sq, off, 64);
    }
    s = __shfl(s, 0, 64);
    sq = __shfl(sq, 0, 64);
    float mean = s * (1.0f / DD);
    float var = sq * (1.0f / DD) - mean * mean;
    float rstd = rsqrtf(var + 1e-5f);
    __hip_bfloat16* yp = y + (size_t)row * DD + lane * 2;
    yp[0] = __float2bfloat16((v.x - mean) * rstd * gg.x + bb.x);
    yp[1] = __float2bfloat16((v.y - mean) * rstd * gg.y + bb.y);
}

// avg + LN -> fp32 out (for final projection)
__global__ __launch_bounds__(256) void avgln_kernel(
    const float* __restrict__ xa, const float* __restrict__ xb,
    const float* __restrict__ g, const float* __restrict__ b, float* __restrict__ y)
{
    int wave = threadIdx.x >> 6;
    int lane = threadIdx.x & 63;
    int row = blockIdx.x * 4 + wave;
    float2 va = ((const float2*)(xa + (size_t)row * DD))[lane];
    float2 vb = ((const float2*)(xb + (size_t)row * DD))[lane];
    float2 v = make_float2((va.x + vb.x) * 0.5f, (va.y + vb.y) * 0.5f);
    float2 gg = ((const float2*)g)[lane];
    float2 bb = ((const float2*)b)[lane];
    float s = v.x + v.y;
    float sq = v.x * v.x + v.y * v.y;
    #pragma unroll
    for (int off = 32; off > 0; off >>= 1) {
        s += __shfl_down(s, off, 64);
        sq += __shfl_down(sq, off, 64);
    }
    s = __shfl(s, 0, 64);
    sq = __shfl(sq, 0, 64);
    float mean = s * (1.0f / DD);
    float var = sq * (1.0f / DD) - mean * mean;
    float rstd = rsqrtf(var + 1e-5f);
    float2 o;
    o.x = (v.x - mean) * rstd * gg.x + bb.x;
    o.y = (v.y - mean) * rstd * gg.y + bb.y;
    ((float2*)(y + (size_t)row * DD))[lane] = o;
}

// ---------------- bf16 MFMA GEMM ----------------
// A[M,K] bf16 row-major, Bt[N,K] bf16 row-major (i.e. W transposed)
// Block: 256 thr = 4 waves (2x2), BM=64, BN=128, K-tile=128
// LDS swizzle: 16B chunk c of row r stored at chunk slot r*16 + (c ^ (r&7))
__device__ __forceinline__ float gelu_exact(float x) {
    return 0.5f * x * (1.0f + erff(x * 0.70710678118654752f));
}

template<int K, int N, bool BIAS, bool RES, bool GELU, bool OBF>
__global__ __launch_bounds__(256) void gemm_bf16(
    const __hip_bfloat16* __restrict__ A, const __hip_bfloat16* __restrict__ Bt,
    const float* __restrict__ bias, const float* __restrict__ Rsrc,
    void* __restrict__ Cdst)
{
    __shared__ unsigned short As[64 * 128];    // 16 KB
    __shared__ unsigned short Bs[128 * 128];   // 32 KB
    int tid = threadIdx.x;
    int l = tid & 63, w = tid >> 6;
    int wr = w >> 1, wc = w & 1;
    int lr = l & 15, q = l >> 4;
    int m0 = blockIdx.y * 64;
    int n0 = blockIdx.x * 128;

    f32x4 acc[2][4];
    #pragma unroll
    for (int mt = 0; mt < 2; ++mt)
        #pragma unroll
        for (int nt = 0; nt < 4; ++nt) acc[mt][nt] = (f32x4){0.f, 0.f, 0.f, 0.f};

    for (int kt = 0; kt < K; kt += 128) {
        if (kt) __syncthreads();
        #pragma unroll
        for (int p = 0; p < 4; ++p) {
            int n = p * 256 + tid;
            int r = n >> 4;
            int c = (n & 15) ^ (r & 7);
            uint4 dv = *(const uint4*)(A + (size_t)(m0 + r) * K + kt + c * 8);
            *(uint4*)&As[n * 8] = dv;
        }
        #pragma unroll
        for (int p = 0; p < 8; ++p) {
            int n = p * 256 + tid;
            int r = n >> 4;
            int c = (n & 15) ^ (r & 7);
            uint4 dv = *(const uint4*)(Bt + (size_t)(n0 + r) * K + kt + c * 8);
            *(uint4*)&Bs[n * 8] = dv;
        }
        __syncthreads();

        #pragma unroll
        for (int kk = 0; kk < 4; ++kk) {
            bf16x8 afr[2], bfr[4];
            #pragma unroll
            for (int mt = 0; mt < 2; ++mt) {
                int rA = wr * 32 + mt * 16 + lr;
                int cc = (kk * 4 + q) ^ (rA & 7);
                afr[mt] = *(const bf16x8*)&As[(rA * 16 + cc) * 8];
            }
            #pragma unroll
            for (int nt = 0; nt < 4; ++nt) {
                int rB = wc * 64 + nt * 16 + lr;
                int cc = (kk * 4 + q) ^ (rB & 7);
                bfr[nt] = *(const bf16x8*)&Bs[(rB * 16 + cc) * 8];
            }
            #pragma unroll
            for (int mt = 0; mt < 2; ++mt)
                #pragma unroll
                for (int nt = 0; nt < 4; ++nt)
                    acc[mt][nt] = __builtin_amdgcn_mfma_f32_16x16x32_bf16(
                        afr[mt], bfr[nt], acc[mt][nt], 0, 0, 0);
        }
    }

    // epilogue: C layout col=lane&15, row=(lane>>4)*4+reg
    #pragma unroll
    for (int mt = 0; mt < 2; ++mt) {
        #pragma unroll
        for (int nt = 0; nt < 4; ++nt) {
            int col = n0 + wc * 64 + nt * 16 + lr;
            float bv = BIAS ? bias[col] : 0.f;
            #pragma unroll
            for (int r = 0; r < 4; ++r) {
                int row = m0 + wr * 32 + mt * 16 + q * 4 + r;
                float val = acc[mt][nt][r] + bv;
                if (GELU) val = gelu_exact(val);
                if (RES) val += Rsrc[(size_t)row * N + col];
                if (OBF) ((__hip_bfloat16*)Cdst)[(size_t)row * N + col] = __float2bfloat16(val);
                else     ((float*)Cdst)[(size_t)row * N + col] = val;
            }
        }
    }
}

// ---------------- attention v3: 4 lanes per query, quarter-blocks ----------------
// qkv layout: [B*L, 256] fp32, qk in cols 0..127 (head h at h*16), v in cols 128..255.
// s_j = (q.khat_j)/4 = c*(qhat.khat_j), c = |q|/4; fixed max mfix = c (Cauchy-Schwarz):
// p = exp(c*(qhat.khat - 1)) in (0,1]. Self term underflows to 0 as in reference; i==0 -> o=v_0.
__global__ __launch_bounds__(384, 4) void attn_kernel(
    const float* __restrict__ qkv, __hip_bfloat16* __restrict__ o)
{
    int quarter = blockIdx.x & 3;
    int bh = blockIdx.x >> 2;
    int b = bh >> 3, hh = bh & 7;
    const float* base = qkv + (size_t)b * LL * 256 + hh * DHH;
    __shared__ float kn[LL][20];   // normalized k, padded row (conflict-free 4-row reads)
    __shared__ float vs[LL][20];
    __shared__ float cq[LL];       // 0.25*|q|
    int t = threadIdx.x;
    int nstage = (quarter + 1) * 96;
    if (t < nstage) {
        const float* qp = base + (size_t)t * 256;
        float q[16], vv16[16];
        #pragma unroll
        for (int c = 0; c < 4; ++c) {
            *(float4*)&q[c * 4]    = *(const float4*)(qp + c * 4);
            *(float4*)&vv16[c * 4] = *(const float4*)(qp + 128 + c * 4);
        }
        float nrm = 0.f;
        #pragma unroll
        for (int d = 0; d < 16; ++d) nrm = fmaf(q[d], q[d], nrm);
        float qn = sqrtf(nrm);
        float inv = 1.0f / fmaxf(qn, 1e-12f);
        cq[t] = 0.25f * qn;
        #pragma unroll
        for (int c = 0; c < 4; ++c) {
            float4 kv;
            kv.x = q[c*4+0] * inv; kv.y = q[c*4+1] * inv;
            kv.z = q[c*4+2] * inv; kv.w = q[c*4+3] * inv;
            *(float4*)&kn[t][c * 4] = kv;
            *(float4*)&vs[t][c * 4] = *(const float4*)&vv16[c * 4];
        }
    }
    __syncthreads();

    int i = quarter * 96 + (t >> 2);
    int sub = t & 3;
    float qh[16];
    #pragma unroll
    for (int c = 0; c < 4; ++c)
        *(float4*)&qh[c * 4] = *(const float4*)&kn[i][c * 4];
    float cc = cq[i];

    float l = 0.f;
    float acc[16];
    #pragma unroll
    for (int d = 0; d < 16; ++d) acc[d] = 0.f;

    auto body = [&](int j) {
        float kj[16], vj[16];
        #pragma unroll
        for (int c = 0; c < 4; ++c) {
            *(float4*)&kj[c * 4] = *(const float4*)&kn[j][c * 4];
            *(float4*)&vj[c * 4] = *(const float4*)&vs[j][c * 4];
        }
        float d0 = 0.f, d1 = 0.f, d2 = 0.f, d3 = 0.f;
        #pragma unroll
        for (int dd = 0; dd < 4; ++dd) {
            d0 = fmaf(qh[dd],      kj[dd],      d0);
            d1 = fmaf(qh[4 + dd],  kj[4 + dd],  d1);
            d2 = fmaf(qh[8 + dd],  kj[8 + dd],  d2);
            d3 = fmaf(qh[12 + dd], kj[12 + dd], d3);
        }
        float s = (d0 + d1) + (d2 + d3);
        float p = __expf(fmaf(s, cc, -cc));
        l += p;
        #pragma unroll
        for (int dd = 0; dd < 16; ++dd) acc[dd] = fmaf(p, vj[dd], acc[dd]);
    };

    int j = sub;
    for (; j + 4 < i; j += 8) { body(j); body(j + 4); }
    if (j < i) body(j);

    if (i == 0 && sub == 0) {
        l = 1.0f;
        #pragma unroll
        for (int d = 0; d < 16; ++d) acc[d] = vs[0][d];
    }
    l += __shfl_xor(l, 1, 4);
    l += __shfl_xor(l, 2, 4);
    #pragma unroll
    for (int d = 0; d < 16; ++d) {
        acc[d] += __shfl_xor(acc[d], 1, 4);
        acc[d] += __shfl_xor(acc[d], 2, 4);
    }
    float invl = 1.0f / l;
    __hip_bfloat16 pk[4];
    #pragma unroll
    for (int dd = 0; dd < 4; ++dd)
        pk[dd] = __float2bfloat16(acc[sub * 4 + dd] * invl);
    *(ushort4*)((unsigned short*)o + (size_t)(b * LL + i) * DD + hh * 16 + sub * 4)
        = *(ushort4*)&pk[0];
}

// ---------------- final projection [64,49152] x [49152,128] ----------------
__global__ __launch_bounds__(256) void out_init_kernel(
    const float* __restrict__ bp, float* __restrict__ out)
{
    int t = blockIdx.x * 256 + threadIdx.x;   // 8192
    out[t] = bp[t & (COUT - 1)];
}

__global__ __launch_bounds__(256) void final_gemm_kernel(
    const float* __restrict__ xm, const float* __restrict__ Wp,
    float* __restrict__ out)
{
    int mq = blockIdx.x;        // 0..3 -> rows mq*16..+15
    int kc = blockIdx.y;        // 0..95 -> k chunk of 512
    __shared__ float xs[16][516];
    int k0 = kc * 512;
    #pragma unroll
    for (int p = 0; p < 8; ++p) {
        int id = threadIdx.x + p * 256;   // 0..2047 float4s
        int r = id >> 7;
        int c = (id & 127) << 2;
        *(float4*)&xs[r][c] = *(const float4*)(xm + (size_t)(mq * 16 + r) * KP + k0 + c);
    }
    __syncthreads();
    int n4 = (threadIdx.x & 31) << 2;
    int m2 = (threadIdx.x >> 5) << 1;    // 0,2,...,14
    float acc0[4] = {0.f, 0.f, 0.f, 0.f};
    float acc1[4] = {0.f, 0.f, 0.f, 0.f};
    for (int k = 0; k < 512; k += 4) {
        float4 xa = *(const float4*)&xs[m2][k];
        float4 xb = *(const float4*)&xs[m2 + 1][k];
        const float* wrow = Wp + (size_t)(k0 + k) * COUT + n4;
        float4 w0 = *(const float4*)(wrow);
        float4 w1 = *(const float4*)(wrow + COUT);
        float4 w2 = *(const float4*)(wrow + 2 * COUT);
        float4 w3 = *(const float4*)(wrow + 3 * COUT);
        float x0[4] = {xa.x, xa.y, xa.z, xa.w};
        float x1[4] = {xb.x, xb.y, xb.z, xb.w};
        float4 wv[4] = {w0, w1, w2, w3};
        #pragma unroll
        for (int kk = 0; kk < 4; ++kk) {
            acc0[0] = fmaf(x0[kk], wv[kk].x, acc0[0]);
            acc0[1] = fmaf(x0[kk], wv[kk].y, acc0[1]);
            acc0[2] = fmaf(x0[kk], wv[kk].z, acc0[2]);
            acc0[3] = fmaf(x0[kk], wv[kk].w, acc0[3]);
            acc1[0] = fmaf(x1[kk], wv[kk].x, acc1[0]);
            acc1[1] = fmaf(x1[kk], wv[kk].y, acc1[1]);
            acc1[2] = fmaf(x1[kk], wv[kk].z, acc1[2]);
            acc1[3] = fmaf(x1[kk], wv[kk].w, acc1[3]);
        }
    }
    int orow = mq * 16 + m2;
    #pragma unroll
    for (int c = 0; c < 4; ++c) {
        atomicAdd(&out[(size_t)orow * COUT + n4 + c], acc0[c]);
        atomicAdd(&out[(size_t)(orow + 1) * COUT + n4 + c], acc1[c]);
    }
}

// ---------------- launch ----------------
extern "C" void kernel_launch(void* const* d_in, const int* in_sizes, int n_in,
                              void* d_out, int out_size, void* d_ws, size_t ws_size,
                              hipStream_t stream)
{
    const int*   x_enc = (const int*)  d_in[0];
    const float* emb   = (const float*)d_in[1];
    const float* pos1  = (const float*)d_in[2];
    const float* pos2  = (const float*)d_in[3];
    const float* ln1_g = (const float*)d_in[4];
    const float* ln1_b = (const float*)d_in[5];
    const float* Wqk   = (const float*)d_in[6];
    const float* Wv    = (const float*)d_in[7];
    const float* Wo    = (const float*)d_in[8];
    const float* bo    = (const float*)d_in[9];
    const float* ln2_g = (const float*)d_in[10];
    const float* ln2_b = (const float*)d_in[11];
    const float* W1    = (const float*)d_in[12];
    const float* b1    = (const float*)d_in[13];
    const float* W2    = (const float*)d_in[14];
    const float* b2    = (const float*)d_in[15];
    const float* lnf_g = (const float*)d_in[16];
    const float* lnf_b = (const float*)d_in[17];
    const float* Wp    = (const float*)d_in[18];
    const float* bp    = (const float*)d_in[19];
    float* out = (float*)d_out;

    // workspace layout; SZ = 3,145,728 elements
    const size_t SZ = (size_t)MROWS * DD;
    float* ws_f = (float*)d_ws;
    float* x1 = ws_f;                    // fp32 [M,128]
    float* x2 = ws_f + SZ;               // fp32 [M,128]
    float* R  = ws_f + 2 * SZ;           // 2*SZ floats shared region
    float* qkv = R;                      // fp32 [M,256]  (lifetime: qkv-gemm..attn)
    __hip_bfloat16* hff = (__hip_bfloat16*)R;   // bf16 [M,512] (lifetime: ff1..ff2)
    float* hfin = R;                     // fp32 [M,128]  (final LN out)
    __hip_bfloat16* h_bf = (__hip_bfloat16*)(ws_f + 4 * SZ);  // bf16 [M,128]
    __hip_bfloat16* o_bf = h_bf + SZ;                          // bf16 [M,128]
    __hip_bfloat16* wqvT = o_bf + SZ;    // 6 * [256,128]  (Wqk^T rows 0..127, Wv^T rows 128..255)
    __hip_bfloat16* woT  = wqvT + 6 * 32768;         // 6 * [128,128]
    __hip_bfloat16* w1T  = woT  + 6 * 16384;         // 6 * [512,128]
    __hip_bfloat16* w2T  = w1T  + 6 * 65536;         // 6 * [128,512]

    // weight casts (transpose to [N,K] bf16)
    castT_kernel<<<dim3(4, 4, 6),  dim3(256), 0, stream>>>(Wqk, wqvT,         128, 128, 16384, 32768);
    castT_kernel<<<dim3(4, 4, 6),  dim3(256), 0, stream>>>(Wv,  wqvT + 16384, 128, 128, 16384, 32768);
    castT_kernel<<<dim3(4, 4, 6),  dim3(256), 0, stream>>>(Wo,  woT,          128, 128, 16384, 16384);
    castT_kernel<<<dim3(4, 16, 6), dim3(256), 0, stream>>>(W1,  w1T,          128, 512, 65536, 65536);
    castT_kernel<<<dim3(16, 4, 6), dim3(256), 0, stream>>>(W2,  w2T,          512, 128, 65536, 65536);

    embed_kernel<<<dim3(MROWS * 32 / 256), dim3(256), 0, stream>>>(x_enc, emb, pos1, pos2, x1, x2);

    for (int d = 0; d < DEPTH; ++d) {
        const float* l1g = ln1_g + d * DD;
        const float* l1b = ln1_b + d * DD;
        const float* bod = bo + d * DD;
        const float* l2g = ln2_g + d * DD;
        const float* l2b = ln2_b + d * DD;
        const float* b1d = b1 + d * FFD;
        const float* b2d = b2 + d * DD;
        const __hip_bfloat16* wqv_d = wqvT + (size_t)d * 32768;
        const __hip_bfloat16* wo_d  = woT  + (size_t)d * 16384;
        const __hip_bfloat16* w1_d  = w1T  + (size_t)d * 65536;
        const __hip_bfloat16* w2_d  = w2T  + (size_t)d * 65536;

        ln_kernel<<<dim3(MROWS / 4), dim3(256), 0, stream>>>(x2, l1g, l1b, h_bf);
        gemm_bf16<128, 256, false, false, false, false>
            <<<dim3(2, MROWS / 64), dim3(256), 0, stream>>>(h_bf, wqv_d, nullptr, nullptr, qkv);
        attn_kernel<<<dim3(BB * HH * 4), dim3(384), 0, stream>>>(qkv, o_bf);
        gemm_bf16<128, 128, true, true, false, false>
            <<<dim3(1, MROWS / 64), dim3(256), 0, stream>>>(o_bf, wo_d, bod, x1, x1);
        ln_kernel<<<dim3(MROWS / 4), dim3(256), 0, stream>>>(x1, l2g, l2b, h_bf);
        gemm_bf16<128, 512, true, false, true, true>
            <<<dim3(4, MROWS / 64), dim3(256), 0, stream>>>(h_bf, w1_d, b1d, nullptr, hff);
        gemm_bf16<512, 128, true, true, false, false>
            <<<dim3(1, MROWS / 64), dim3(256), 0, stream>>>(hff, w2_d, b2d, x2, x2);
    }

    avgln_kernel<<<dim3(MROWS / 4), dim3(256), 0, stream>>>(x1, x2, lnf_g, lnf_b, hfin);
    out_init_kernel<<<dim3(32), dim3(256), 0, stream>>>(bp, out);
    final_gemm_kernel<<<dim3(4, 96), dim3(256), 0, stream>>>(hfin, Wp, out);
}

// Round 5
// 970.087 us; speedup vs baseline: 1.2452x; 1.2452x over previous
//
#include <hip/hip_runtime.h>
#include <hip/hip_bf16.h>
#include <math.h>

#define BB 64
#define LL 384
#define DD 128
#define HH 8
#define DHH 16
#define DEPTH 6
#define FFD 512
#define MROWS (BB*LL)      // 24576
#define COUT 128
#define KP (LL*DD)         // 49152

typedef short bf16x8 __attribute__((ext_vector_type(8)));
typedef float f32x4 __attribute__((ext_vector_type(4)));

// ---------------- embed + axial pos ----------------
__global__ __launch_bounds__(256) void embed_kernel(
    const int* __restrict__ x_enc, const float* __restrict__ emb,
    const float* __restrict__ pos1, const float* __restrict__ pos2,
    float* __restrict__ x1, float* __restrict__ x2)
{
    int t = blockIdx.x * 256 + threadIdx.x;      // over MROWS * 32 float4
    int row = t >> 5;
    int c4 = t & 31;
    int l = row % LL;
    int tok = x_enc[row];
    float4 a = ((const float4*)(emb + (size_t)tok * DD))[c4];
    float4 b = ((const float4*)(pos1 + (l / 25) * DD))[c4];
    float4 c = ((const float4*)(pos2 + (l % 25) * DD))[c4];
    float4 r = make_float4(a.x + b.x + c.x, a.y + b.y + c.y,
                           a.z + b.z + c.z, a.w + b.w + c.w);
    ((float4*)x1)[t] = r;
    ((float4*)x2)[t] = r;
}

// ---------------- weight cast + transpose: W[K,N] fp32 -> Wt[N,K] bf16 ----------------
__global__ __launch_bounds__(256) void castT_kernel(
    const float* __restrict__ src, __hip_bfloat16* __restrict__ dst, int K, int N,
    long sstride, long dstride)
{
    __shared__ float tile[32][33];
    int kb = blockIdx.x * 32, nb = blockIdx.y * 32;
    int tx = threadIdx.x & 31, ty = threadIdx.x >> 5;   // ty 0..7
    const float* s = src + (size_t)blockIdx.z * sstride;
    __hip_bfloat16* d = dst + (size_t)blockIdx.z * dstride;
    #pragma unroll
    for (int r = 0; r < 32; r += 8)
        tile[r + ty][tx] = s[(size_t)(kb + r + ty) * N + nb + tx];
    __syncthreads();
    #pragma unroll
    for (int r = 0; r < 32; r += 8)
        d[(size_t)(nb + r + ty) * K + kb + tx] = __float2bfloat16(tile[tx][r + ty]);
}

// ---------------- LayerNorm (wave per row) -> bf16 out ----------------
__global__ __launch_bounds__(256) void ln_kernel(
    const float* __restrict__ x, const float* __restrict__ g,
    const float* __restrict__ b, __hip_bfloat16* __restrict__ y)
{
    int wave = threadIdx.x >> 6;
    int lane = threadIdx.x & 63;
    int row = blockIdx.x * 4 + wave;
    float2 v = ((const float2*)(x + (size_t)row * DD))[lane];
    float2 gg = ((const float2*)g)[lane];
    float2 bb = ((const float2*)b)[lane];
    float s = v.x + v.y;
    float sq = v.x * v.x + v.y * v.y;
    #pragma unroll
    for (int off = 32; off > 0; off >>= 1) {
        s += __shfl_down(s, off, 64);
        sq += __shfl_down(sq, off, 64);
    }
    s = __shfl(s, 0, 64);
    sq = __shfl(sq, 0, 64);
    float mean = s * (1.0f / DD);
    float var = sq * (1.0f / DD) - mean * mean;
    float rstd = rsqrtf(var + 1e-5f);
    __hip_bfloat16* yp = y + (size_t)row * DD + lane * 2;
    yp[0] = __float2bfloat16((v.x - mean) * rstd * gg.x + bb.x);
    yp[1] = __float2bfloat16((v.y - mean) * rstd * gg.y + bb.y);
}

// avg + LN -> fp32 out (for final projection)
__global__ __launch_bounds__(256) void avgln_kernel(
    const float* __restrict__ xa, const float* __restrict__ xb,
    const float* __restrict__ g, const float* __restrict__ b, float* __restrict__ y)
{
    int wave = threadIdx.x >> 6;
    int lane = threadIdx.x & 63;
    int row = blockIdx.x * 4 + wave;
    float2 va = ((const float2*)(xa + (size_t)row * DD))[lane];
    float2 vb = ((const float2*)(xb + (size_t)row * DD))[lane];
    float2 v = make_float2((va.x + vb.x) * 0.5f, (va.y + vb.y) * 0.5f);
    float2 gg = ((const float2*)g)[lane];
    float2 bb = ((const float2*)b)[lane];
    float s = v.x + v.y;
    float sq = v.x * v.x + v.y * v.y;
    #pragma unroll
    for (int off = 32; off > 0; off >>= 1) {
        s += __shfl_down(s, off, 64);
        sq += __shfl_down(sq, off, 64);
    }
    s = __shfl(s, 0, 64);
    sq = __shfl(sq, 0, 64);
    float mean = s * (1.0f / DD);
    float var = sq * (1.0f / DD) - mean * mean;
    float rstd = rsqrtf(var + 1e-5f);
    float2 o;
    o.x = (v.x - mean) * rstd * gg.x + bb.x;
    o.y = (v.y - mean) * rstd * gg.y + bb.y;
    ((float2*)(y + (size_t)row * DD))[lane] = o;
}

// ---------------- bf16 MFMA GEMM ----------------
// A[M,K] bf16 row-major, Bt[N,K] bf16 row-major (i.e. W transposed)
// Block: 256 thr = 4 waves (2x2), BM=64, BN=128, K-tile=128
// LDS swizzle: 16B chunk c of row r stored at chunk slot r*16 + (c ^ (r&7))
__device__ __forceinline__ float gelu_exact(float x) {
    return 0.5f * x * (1.0f + erff(x * 0.70710678118654752f));
}

template<int K, int N, bool BIAS, bool RES, bool GELU, bool OBF>
__global__ __launch_bounds__(256) void gemm_bf16(
    const __hip_bfloat16* __restrict__ A, const __hip_bfloat16* __restrict__ Bt,
    const float* __restrict__ bias, const float* __restrict__ Rsrc,
    void* __restrict__ Cdst)
{
    __shared__ unsigned short As[64 * 128];    // 16 KB
    __shared__ unsigned short Bs[128 * 128];   // 32 KB
    int tid = threadIdx.x;
    int l = tid & 63, w = tid >> 6;
    int wr = w >> 1, wc = w & 1;
    int lr = l & 15, q = l >> 4;
    int m0 = blockIdx.y * 64;
    int n0 = blockIdx.x * 128;

    f32x4 acc[2][4];
    #pragma unroll
    for (int mt = 0; mt < 2; ++mt)
        #pragma unroll
        for (int nt = 0; nt < 4; ++nt) acc[mt][nt] = (f32x4){0.f, 0.f, 0.f, 0.f};

    for (int kt = 0; kt < K; kt += 128) {
        if (kt) __syncthreads();
        #pragma unroll
        for (int p = 0; p < 4; ++p) {
            int n = p * 256 + tid;
            int r = n >> 4;
            int c = (n & 15) ^ (r & 7);
            uint4 dv = *(const uint4*)(A + (size_t)(m0 + r) * K + kt + c * 8);
            *(uint4*)&As[n * 8] = dv;
        }
        #pragma unroll
        for (int p = 0; p < 8; ++p) {
            int n = p * 256 + tid;
            int r = n >> 4;
            int c = (n & 15) ^ (r & 7);
            uint4 dv = *(const uint4*)(Bt + (size_t)(n0 + r) * K + kt + c * 8);
            *(uint4*)&Bs[n * 8] = dv;
        }
        __syncthreads();

        #pragma unroll
        for (int kk = 0; kk < 4; ++kk) {
            bf16x8 afr[2], bfr[4];
            #pragma unroll
            for (int mt = 0; mt < 2; ++mt) {
                int rA = wr * 32 + mt * 16 + lr;
                int cc = (kk * 4 + q) ^ (rA & 7);
                afr[mt] = *(const bf16x8*)&As[(rA * 16 + cc) * 8];
            }
            #pragma unroll
            for (int nt = 0; nt < 4; ++nt) {
                int rB = wc * 64 + nt * 16 + lr;
                int cc = (kk * 4 + q) ^ (rB & 7);
                bfr[nt] = *(const bf16x8*)&Bs[(rB * 16 + cc) * 8];
            }
            #pragma unroll
            for (int mt = 0; mt < 2; ++mt)
                #pragma unroll
                for (int nt = 0; nt < 4; ++nt)
                    acc[mt][nt] = __builtin_amdgcn_mfma_f32_16x16x32_bf16(
                        afr[mt], bfr[nt], acc[mt][nt], 0, 0, 0);
        }
    }

    // epilogue: C layout col=lane&15, row=(lane>>4)*4+reg
    #pragma unroll
    for (int mt = 0; mt < 2; ++mt) {
        #pragma unroll
        for (int nt = 0; nt < 4; ++nt) {
            int col = n0 + wc * 64 + nt * 16 + lr;
            float bv = BIAS ? bias[col] : 0.f;
            #pragma unroll
            for (int r = 0; r < 4; ++r) {
                int row = m0 + wr * 32 + mt * 16 + q * 4 + r;
                float val = acc[mt][nt][r] + bv;
                if (GELU) val = gelu_exact(val);
                if (RES) val += Rsrc[(size_t)row * N + col];
                if (OBF) ((__hip_bfloat16*)Cdst)[(size_t)row * N + col] = __float2bfloat16(val);
                else     ((float*)Cdst)[(size_t)row * N + col] = val;
            }
        }
    }
}

// ---------------- attention v5: 2 lanes/query, half-blocks, no register arrays ----------------
// qkv layout: [B*L, 256] fp32, qk at cols hh*16.., v at 128+hh*16..
// p = exp(cc*(qhat.khat - 1)), cc = |q|/4 (Cauchy-Schwarz fixed max).
// Self term underflows to 0 as in reference; i==0 -> o = v_0.
__global__ __launch_bounds__(384) void attn_kernel(
    const float* __restrict__ qkv, __hip_bfloat16* __restrict__ o)
{
    int h2 = (blockIdx.x < 512) ? 1 : 0;         // heavy halves dispatched first
    int bh = blockIdx.x & 511;
    int b = bh >> 3, hh = bh & 7;
    const float* base = qkv + (size_t)b * LL * 256 + hh * DHH;
    __shared__ float kn[LL][DHH];
    __shared__ float vs[LL][DHH];
    __shared__ float cq[LL];
    int t = threadIdx.x;
    int hi = h2 ? LL : 192;
    if (t < hi) {
        const float* qp = base + (size_t)t * 256;
        float q[16];
        #pragma unroll
        for (int c = 0; c < 4; ++c)
            *(float4*)&q[c * 4] = *(const float4*)(qp + c * 4);
        float nrm = 0.f;
        #pragma unroll
        for (int d = 0; d < 16; ++d) nrm = fmaf(q[d], q[d], nrm);
        float qn = sqrtf(nrm);
        float inv = 1.0f / fmaxf(qn, 1e-12f);
        cq[t] = 0.25f * qn;
        #pragma unroll
        for (int c = 0; c < 4; ++c) {
            float4 kv;
            kv.x = q[c*4+0] * inv; kv.y = q[c*4+1] * inv;
            kv.z = q[c*4+2] * inv; kv.w = q[c*4+3] * inv;
            *(float4*)&kn[t][c * 4] = kv;
            *(float4*)&vs[t][c * 4] = *(const float4*)(qp + 128 + c * 4);
        }
    }
    __syncthreads();

    int qi = h2 * 192 + (t >> 1);
    int sub = t & 1;
    float qh[16];
    #pragma unroll
    for (int c = 0; c < 4; ++c)
        *(float4*)&qh[c * 4] = *(const float4*)&kn[qi][c * 4];
    float cc = cq[qi];

    float l = 0.f;
    float acc[16];
    #pragma unroll
    for (int d = 0; d < 16; ++d) acc[d] = 0.f;

    auto body = [&](int j) {
        float4 k0 = *(const float4*)&kn[j][0];
        float4 k1 = *(const float4*)&kn[j][4];
        float4 k2 = *(const float4*)&kn[j][8];
        float4 k3 = *(const float4*)&kn[j][12];
        float d0 = fmaf(qh[0],  k0.x, fmaf(qh[1],  k0.y, fmaf(qh[2],  k0.z, qh[3]  * k0.w)));
        float d1 = fmaf(qh[4],  k1.x, fmaf(qh[5],  k1.y, fmaf(qh[6],  k1.z, qh[7]  * k1.w)));
        float d2 = fmaf(qh[8],  k2.x, fmaf(qh[9],  k2.y, fmaf(qh[10], k2.z, qh[11] * k2.w)));
        float d3 = fmaf(qh[12], k3.x, fmaf(qh[13], k3.y, fmaf(qh[14], k3.z, qh[15] * k3.w)));
        float s = (d0 + d1) + (d2 + d3);
        float4 v0 = *(const float4*)&vs[j][0];
        float4 v1 = *(const float4*)&vs[j][4];
        float4 v2 = *(const float4*)&vs[j][8];
        float4 v3 = *(const float4*)&vs[j][12];
        float p = __expf(fmaf(s, cc, -cc));
        l += p;
        acc[0]  = fmaf(p, v0.x, acc[0]);  acc[1]  = fmaf(p, v0.y, acc[1]);
        acc[2]  = fmaf(p, v0.z, acc[2]);  acc[3]  = fmaf(p, v0.w, acc[3]);
        acc[4]  = fmaf(p, v1.x, acc[4]);  acc[5]  = fmaf(p, v1.y, acc[5]);
        acc[6]  = fmaf(p, v1.z, acc[6]);  acc[7]  = fmaf(p, v1.w, acc[7]);
        acc[8]  = fmaf(p, v2.x, acc[8]);  acc[9]  = fmaf(p, v2.y, acc[9]);
        acc[10] = fmaf(p, v2.z, acc[10]); acc[11] = fmaf(p, v2.w, acc[11]);
        acc[12] = fmaf(p, v3.x, acc[12]); acc[13] = fmaf(p, v3.y, acc[13]);
        acc[14] = fmaf(p, v3.z, acc[14]); acc[15] = fmaf(p, v3.w, acc[15]);
    };

    int j = sub;
    for (; j + 2 < qi; j += 4) { body(j); body(j + 2); }
    if (j < qi) body(j);

    if (qi == 0 && sub == 0) {
        l = 1.0f;
        #pragma unroll
        for (int d = 0; d < 16; ++d) acc[d] = vs[0][d];
    }
    // combine the lane pair (lanes 2q, 2q+1)
    l += __shfl_xor(l, 1);
    #pragma unroll
    for (int d = 0; d < 16; ++d) acc[d] += __shfl_xor(acc[d], 1);

    float invl = 1.0f / l;
    __hip_bfloat16 pk[8];
    #pragma unroll
    for (int d = 0; d < 8; ++d)
        pk[d] = __float2bfloat16(acc[sub * 8 + d] * invl);
    *(uint4*)((unsigned short*)o + (size_t)(b * LL + qi) * DD + hh * 16 + sub * 8)
        = *(uint4*)&pk[0];
}

// ---------------- final projection [64,49152] x [49152,128] ----------------
__global__ __launch_bounds__(256) void out_init_kernel(
    const float* __restrict__ bp, float* __restrict__ out)
{
    int t = blockIdx.x * 256 + threadIdx.x;   // 8192
    out[t] = bp[t & (COUT - 1)];
}

__global__ __launch_bounds__(256) void final_gemm_kernel(
    const float* __restrict__ xm, const float* __restrict__ Wp,
    float* __restrict__ out)
{
    int mq = blockIdx.x;        // 0..3 -> rows mq*16..+15
    int kc = blockIdx.y;        // 0..95 -> k chunk of 512
    __shared__ float xs[16][516];
    int k0 = kc * 512;
    #pragma unroll
    for (int p = 0; p < 8; ++p) {
        int id = threadIdx.x + p * 256;   // 0..2047 float4s
        int r = id >> 7;
        int c = (id & 127) << 2;
        *(float4*)&xs[r][c] = *(const float4*)(xm + (size_t)(mq * 16 + r) * KP + k0 + c);
    }
    __syncthreads();
    int n4 = (threadIdx.x & 31) << 2;
    int m2 = (threadIdx.x >> 5) << 1;    // 0,2,...,14
    float acc0[4] = {0.f, 0.f, 0.f, 0.f};
    float acc1[4] = {0.f, 0.f, 0.f, 0.f};
    for (int k = 0; k < 512; k += 4) {
        float4 xa = *(const float4*)&xs[m2][k];
        float4 xb = *(const float4*)&xs[m2 + 1][k];
        const float* wrow = Wp + (size_t)(k0 + k) * COUT + n4;
        float4 w0 = *(const float4*)(wrow);
        float4 w1 = *(const float4*)(wrow + COUT);
        float4 w2 = *(const float4*)(wrow + 2 * COUT);
        float4 w3 = *(const float4*)(wrow + 3 * COUT);
        float x0[4] = {xa.x, xa.y, xa.z, xa.w};
        float x1[4] = {xb.x, xb.y, xb.z, xb.w};
        float4 wv[4] = {w0, w1, w2, w3};
        #pragma unroll
        for (int kk = 0; kk < 4; ++kk) {
            acc0[0] = fmaf(x0[kk], wv[kk].x, acc0[0]);
            acc0[1] = fmaf(x0[kk], wv[kk].y, acc0[1]);
            acc0[2] = fmaf(x0[kk], wv[kk].z, acc0[2]);
            acc0[3] = fmaf(x0[kk], wv[kk].w, acc0[3]);
            acc1[0] = fmaf(x1[kk], wv[kk].x, acc1[0]);
            acc1[1] = fmaf(x1[kk], wv[kk].y, acc1[1]);
            acc1[2] = fmaf(x1[kk], wv[kk].z, acc1[2]);
            acc1[3] = fmaf(x1[kk], wv[kk].w, acc1[3]);
        }
    }
    int orow = mq * 16 + m2;
    #pragma unroll
    for (int c = 0; c < 4; ++c) {
        atomicAdd(&out[(size_t)orow * COUT + n4 + c], acc0[c]);
        atomicAdd(&out[(size_t)(orow + 1) * COUT + n4 + c], acc1[c]);
    }
}

// ---------------- launch ----------------
extern "C" void kernel_launch(void* const* d_in, const int* in_sizes, int n_in,
                              void* d_out, int out_size, void* d_ws, size_t ws_size,
                              hipStream_t stream)
{
    const int*   x_enc = (const int*)  d_in[0];
    const float* emb   = (const float*)d_in[1];
    const float* pos1  = (const float*)d_in[2];
    const float* pos2  = (const float*)d_in[3];
    const float* ln1_g = (const float*)d_in[4];
    const float* ln1_b = (const float*)d_in[5];
    const float* Wqk   = (const float*)d_in[6];
    const float* Wv    = (const float*)d_in[7];
    const float* Wo    = (const float*)d_in[8];
    const float* bo    = (const float*)d_in[9];
    const float* ln2_g = (const float*)d_in[10];
    const float* ln2_b = (const float*)d_in[11];
    const float* W1    = (const float*)d_in[12];
    const float* b1    = (const float*)d_in[13];
    const float* W2    = (const float*)d_in[14];
    const float* b2    = (const float*)d_in[15];
    const float* lnf_g = (const float*)d_in[16];
    const float* lnf_b = (const float*)d_in[17];
    const float* Wp    = (const float*)d_in[18];
    const float* bp    = (const float*)d_in[19];
    float* out = (float*)d_out;

    // workspace layout; SZ = 3,145,728 elements
    const size_t SZ = (size_t)MROWS * DD;
    float* ws_f = (float*)d_ws;
    float* x1 = ws_f;                    // fp32 [M,128]
    float* x2 = ws_f + SZ;               // fp32 [M,128]
    float* R  = ws_f + 2 * SZ;           // 2*SZ floats shared region
    float* qkv = R;                      // fp32 [M,256]  (lifetime: qkv-gemm..attn)
    __hip_bfloat16* hff = (__hip_bfloat16*)R;   // bf16 [M,512] (lifetime: ff1..ff2)
    float* hfin = R;                     // fp32 [M,128]  (final LN out)
    __hip_bfloat16* h_bf = (__hip_bfloat16*)(ws_f + 4 * SZ);  // bf16 [M,128]
    __hip_bfloat16* o_bf = h_bf + SZ;                          // bf16 [M,128]
    __hip_bfloat16* wqvT = o_bf + SZ;    // 6 * [256,128]  (Wqk^T rows 0..127, Wv^T rows 128..255)
    __hip_bfloat16* woT  = wqvT + 6 * 32768;         // 6 * [128,128]
    __hip_bfloat16* w1T  = woT  + 6 * 16384;         // 6 * [512,128]
    __hip_bfloat16* w2T  = w1T  + 6 * 65536;         // 6 * [128,512]

    // weight casts (transpose to [N,K] bf16)
    castT_kernel<<<dim3(4, 4, 6),  dim3(256), 0, stream>>>(Wqk, wqvT,         128, 128, 16384, 32768);
    castT_kernel<<<dim3(4, 4, 6),  dim3(256), 0, stream>>>(Wv,  wqvT + 16384, 128, 128, 16384, 32768);
    castT_kernel<<<dim3(4, 4, 6),  dim3(256), 0, stream>>>(Wo,  woT,          128, 128, 16384, 16384);
    castT_kernel<<<dim3(4, 16, 6), dim3(256), 0, stream>>>(W1,  w1T,          128, 512, 65536, 65536);
    castT_kernel<<<dim3(16, 4, 6), dim3(256), 0, stream>>>(W2,  w2T,          512, 128, 65536, 65536);

    embed_kernel<<<dim3(MROWS * 32 / 256), dim3(256), 0, stream>>>(x_enc, emb, pos1, pos2, x1, x2);

    for (int d = 0; d < DEPTH; ++d) {
        const float* l1g = ln1_g + d * DD;
        const float* l1b = ln1_b + d * DD;
        const float* bod = bo + d * DD;
        const float* l2g = ln2_g + d * DD;
        const float* l2b = ln2_b + d * DD;
        const float* b1d = b1 + d * FFD;
        const float* b2d = b2 + d * DD;
        const __hip_bfloat16* wqv_d = wqvT + (size_t)d * 32768;
        const __hip_bfloat16* wo_d  = woT  + (size_t)d * 16384;
        const __hip_bfloat16* w1_d  = w1T  + (size_t)d * 65536;
        const __hip_bfloat16* w2_d  = w2T  + (size_t)d * 65536;

        ln_kernel<<<dim3(MROWS / 4), dim3(256), 0, stream>>>(x2, l1g, l1b, h_bf);
        gemm_bf16<128, 256, false, false, false, false>
            <<<dim3(2, MROWS / 64), dim3(256), 0, stream>>>(h_bf, wqv_d, nullptr, nullptr, qkv);
        attn_kernel<<<dim3(BB * HH * 2), dim3(384), 0, stream>>>(qkv, o_bf);
        gemm_bf16<128, 128, true, true, false, false>
            <<<dim3(1, MROWS / 64), dim3(256), 0, stream>>>(o_bf, wo_d, bod, x1, x1);
        ln_kernel<<<dim3(MROWS / 4), dim3(256), 0, stream>>>(x1, l2g, l2b, h_bf);
        gemm_bf16<128, 512, true, false, true, true>
            <<<dim3(4, MROWS / 64), dim3(256), 0, stream>>>(h_bf, w1_d, b1d, nullptr, hff);
        gemm_bf16<512, 128, true, true, false, false>
            <<<dim3(1, MROWS / 64), dim3(256), 0, stream>>>(hff, w2_d, b2d, x2, x2);
    }

    avgln_kernel<<<dim3(MROWS / 4), dim3(256), 0, stream>>>(x1, x2, lnf_g, lnf_b, hfin);
    out_init_kernel<<<dim3(32), dim3(256), 0, stream>>>(bp, out);
    final_gemm_kernel<<<dim3(4, 96), dim3(256), 0, stream>>>(hfin, Wp, out);
}

// Round 7
// 702.133 us; speedup vs baseline: 1.7205x; 1.3816x over previous
//
#include <hip/hip_runtime.h>
#include <hip/hip_bf16.h>
#include <math.h>

#define BB 64
#define LL 384
#define DD 128
#define HH 8
#define DHH 16
#define DEPTH 6
#define FFD 512
#define MROWS (BB*LL)      // 24576
#define COUT 128
#define KP (LL*DD)         // 49152

typedef short bf16x8 __attribute__((ext_vector_type(8)));
typedef float f32x4 __attribute__((ext_vector_type(4)));

__device__ __forceinline__ unsigned short f2bs(float x) {
    __hip_bfloat16 h = __float2bfloat16(x);
    return *reinterpret_cast<unsigned short*>(&h);
}
__device__ __forceinline__ float bs2f(unsigned short u) {
    unsigned int v = ((unsigned int)u) << 16;
    return __uint_as_float(v);
}

// ---------------- embed + axial pos ----------------
__global__ __launch_bounds__(256) void embed_kernel(
    const int* __restrict__ x_enc, const float* __restrict__ emb,
    const float* __restrict__ pos1, const float* __restrict__ pos2,
    float* __restrict__ x1, float* __restrict__ x2)
{
    int t = blockIdx.x * 256 + threadIdx.x;      // over MROWS * 32 float4
    int row = t >> 5;
    int c4 = t & 31;
    int l = row % LL;
    int tok = x_enc[row];
    float4 a = ((const float4*)(emb + (size_t)tok * DD))[c4];
    float4 b = ((const float4*)(pos1 + (l / 25) * DD))[c4];
    float4 c = ((const float4*)(pos2 + (l % 25) * DD))[c4];
    float4 r = make_float4(a.x + b.x + c.x, a.y + b.y + c.y,
                           a.z + b.z + c.z, a.w + b.w + c.w);
    ((float4*)x1)[t] = r;
    ((float4*)x2)[t] = r;
}

// ---------------- weight cast + transpose: W[K,N] fp32 -> Wt[N,K] bf16 ----------------
__global__ __launch_bounds__(256) void castT_kernel(
    const float* __restrict__ src, __hip_bfloat16* __restrict__ dst, int K, int N,
    long sstride, long dstride)
{
    __shared__ float tile[32][33];
    int kb = blockIdx.x * 32, nb = blockIdx.y * 32;
    int tx = threadIdx.x & 31, ty = threadIdx.x >> 5;   // ty 0..7
    const float* s = src + (size_t)blockIdx.z * sstride;
    __hip_bfloat16* d = dst + (size_t)blockIdx.z * dstride;
    #pragma unroll
    for (int r = 0; r < 32; r += 8)
        tile[r + ty][tx] = s[(size_t)(kb + r + ty) * N + nb + tx];
    __syncthreads();
    #pragma unroll
    for (int r = 0; r < 32; r += 8)
        d[(size_t)(nb + r + ty) * K + kb + tx] = __float2bfloat16(tile[tx][r + ty]);
}

// ---------------- LayerNorm (wave per row) -> bf16 out ----------------
__global__ __launch_bounds__(256) void ln_kernel(
    const float* __restrict__ x, const float* __restrict__ g,
    const float* __restrict__ b, __hip_bfloat16* __restrict__ y)
{
    int wave = threadIdx.x >> 6;
    int lane = threadIdx.x & 63;
    int row = blockIdx.x * 4 + wave;
    float2 v = ((const float2*)(x + (size_t)row * DD))[lane];
    float2 gg = ((const float2*)g)[lane];
    float2 bb = ((const float2*)b)[lane];
    float s = v.x + v.y;
    float sq = v.x * v.x + v.y * v.y;
    #pragma unroll
    for (int off = 32; off > 0; off >>= 1) {
        s += __shfl_down(s, off, 64);
        sq += __shfl_down(sq, off, 64);
    }
    s = __shfl(s, 0, 64);
    sq = __shfl(sq, 0, 64);
    float mean = s * (1.0f / DD);
    float var = sq * (1.0f / DD) - mean * mean;
    float rstd = rsqrtf(var + 1e-5f);
    __hip_bfloat16* yp = y + (size_t)row * DD + lane * 2;
    yp[0] = __float2bfloat16((v.x - mean) * rstd * gg.x + bb.x);
    yp[1] = __float2bfloat16((v.y - mean) * rstd * gg.y + bb.y);
}

// avg + LN -> fp32 out (for final projection)
__global__ __launch_bounds__(256) void avgln_kernel(
    const float* __restrict__ xa, const float* __restrict__ xb,
    const float* __restrict__ g, const float* __restrict__ b, float* __restrict__ y)
{
    int wave = threadIdx.x >> 6;
    int lane = threadIdx.x & 63;
    int row = blockIdx.x * 4 + wave;
    float2 va = ((const float2*)(xa + (size_t)row * DD))[lane];
    float2 vb = ((const float2*)(xb + (size_t)row * DD))[lane];
    float2 v = make_float2((va.x + vb.x) * 0.5f, (va.y + vb.y) * 0.5f);
    float2 gg = ((const float2*)g)[lane];
    float2 bb = ((const float2*)b)[lane];
    float s = v.x + v.y;
    float sq = v.x * v.x + v.y * v.y;
    #pragma unroll
    for (int off = 32; off > 0; off >>= 1) {
        s += __shfl_down(s, off, 64);
        sq += __shfl_down(sq, off, 64);
    }
    s = __shfl(s, 0, 64);
    sq = __shfl(sq, 0, 64);
    float mean = s * (1.0f / DD);
    float var = sq * (1.0f / DD) - mean * mean;
    float rstd = rsqrtf(var + 1e-5f);
    float2 o;
    o.x = (v.x - mean) * rstd * gg.x + bb.x;
    o.y = (v.y - mean) * rstd * gg.y + bb.y;
    ((float2*)(y + (size_t)row * DD))[lane] = o;
}

// ---------------- bf16 MFMA GEMM ----------------
__device__ __forceinline__ float gelu_exact(float x) {
    return 0.5f * x * (1.0f + erff(x * 0.70710678118654752f));
}

template<int K, int N, bool BIAS, bool RES, bool GELU, bool OBF>
__global__ __launch_bounds__(256) void gemm_bf16(
    const __hip_bfloat16* __restrict__ A, const __hip_bfloat16* __restrict__ Bt,
    const float* __restrict__ bias, const float* __restrict__ Rsrc,
    void* __restrict__ Cdst)
{
    __shared__ unsigned short As[64 * 128];    // 16 KB
    __shared__ unsigned short Bs[128 * 128];   // 32 KB
    int tid = threadIdx.x;
    int l = tid & 63, w = tid >> 6;
    int wr = w >> 1, wc = w & 1;
    int lr = l & 15, q = l >> 4;
    int m0 = blockIdx.y * 64;
    int n0 = blockIdx.x * 128;

    f32x4 acc[2][4];
    #pragma unroll
    for (int mt = 0; mt < 2; ++mt)
        #pragma unroll
        for (int nt = 0; nt < 4; ++nt) acc[mt][nt] = (f32x4){0.f, 0.f, 0.f, 0.f};

    for (int kt = 0; kt < K; kt += 128) {
        if (kt) __syncthreads();
        #pragma unroll
        for (int p = 0; p < 4; ++p) {
            int n = p * 256 + tid;
            int r = n >> 4;
            int c = (n & 15) ^ (r & 7);
            uint4 dv = *(const uint4*)(A + (size_t)(m0 + r) * K + kt + c * 8);
            *(uint4*)&As[n * 8] = dv;
        }
        #pragma unroll
        for (int p = 0; p < 8; ++p) {
            int n = p * 256 + tid;
            int r = n >> 4;
            int c = (n & 15) ^ (r & 7);
            uint4 dv = *(const uint4*)(Bt + (size_t)(n0 + r) * K + kt + c * 8);
            *(uint4*)&Bs[n * 8] = dv;
        }
        __syncthreads();

        #pragma unroll
        for (int kk = 0; kk < 4; ++kk) {
            bf16x8 afr[2], bfr[4];
            #pragma unroll
            for (int mt = 0; mt < 2; ++mt) {
                int rA = wr * 32 + mt * 16 + lr;
                int cc = (kk * 4 + q) ^ (rA & 7);
                afr[mt] = *(const bf16x8*)&As[(rA * 16 + cc) * 8];
            }
            #pragma unroll
            for (int nt = 0; nt < 4; ++nt) {
                int rB = wc * 64 + nt * 16 + lr;
                int cc = (kk * 4 + q) ^ (rB & 7);
                bfr[nt] = *(const bf16x8*)&Bs[(rB * 16 + cc) * 8];
            }
            #pragma unroll
            for (int mt = 0; mt < 2; ++mt)
                #pragma unroll
                for (int nt = 0; nt < 4; ++nt)
                    acc[mt][nt] = __builtin_amdgcn_mfma_f32_16x16x32_bf16(
                        afr[mt], bfr[nt], acc[mt][nt], 0, 0, 0);
        }
    }

    // epilogue: C layout col=lane&15, row=(lane>>4)*4+reg
    #pragma unroll
    for (int mt = 0; mt < 2; ++mt) {
        #pragma unroll
        for (int nt = 0; nt < 4; ++nt) {
            int col = n0 + wc * 64 + nt * 16 + lr;
            float bv = BIAS ? bias[col] : 0.f;
            #pragma unroll
            for (int r = 0; r < 4; ++r) {
                int row = m0 + wr * 32 + mt * 16 + q * 4 + r;
                float val = acc[mt][nt][r] + bv;
                if (GELU) val = gelu_exact(val);
                if (RES) val += Rsrc[(size_t)row * N + col];
                if (OBF) ((__hip_bfloat16*)Cdst)[(size_t)row * N + col] = __float2bfloat16(val);
                else     ((float*)Cdst)[(size_t)row * N + col] = val;
            }
        }
    }
}

// ---------------- attention v6b: MFMA flash-style (pad regions zeroed) ----------------
// Per (b,h): S-tile = Qhat.Khat^T via mfma_16x16x32 (d=16 zero-padded to K=32).
// CRITICAL: zero-padding is only safe if the "don't care" B-operand data is FINITE
// (MFMA 0*NaN = NaN) -> knb cols 16..23 and vtb cols 384..407 are explicitly zeroed.
__global__ __launch_bounds__(256) void attn_kernel(
    const float* __restrict__ qkv, __hip_bfloat16* __restrict__ o)
{
    int z  = blockIdx.x & 1;
    int bh = blockIdx.x >> 1;
    int b = bh >> 3, hh = bh & 7;
    const float* base = qkv + (size_t)b * LL * 256 + hh * DHH;

    __shared__ unsigned short knb[LL + 2][24];   // qhat/khat bf16; cols 16..23 zeroed
    __shared__ unsigned short vtb[16][LL + 24];  // V^T bf16; cols 384..407 zeroed
    __shared__ float cq[LL];                     // 0.25*|q|
    __shared__ unsigned short ptile[4][16][40];  // per-wave P tile; cols 16..31 zeroed

    int t = threadIdx.x;
    for (int r = t; r < LL; r += 256) {
        const float* qp = base + (size_t)r * 256;
        float q[16], vv[16];
        #pragma unroll
        for (int c = 0; c < 4; ++c) {
            *(float4*)&q[c * 4]  = *(const float4*)(qp + c * 4);
            *(float4*)&vv[c * 4] = *(const float4*)(qp + 128 + c * 4);
        }
        float nrm = 0.f;
        #pragma unroll
        for (int d = 0; d < 16; ++d) nrm = fmaf(q[d], q[d], nrm);
        float qn = sqrtf(nrm);
        float inv = 1.0f / fmaxf(qn, 1e-12f);
        cq[r] = 0.25f * qn;
        unsigned short kb[16];
        #pragma unroll
        for (int d = 0; d < 16; ++d) kb[d] = f2bs(q[d] * inv);
        *(uint4*)&knb[r][0] = *(uint4*)&kb[0];
        *(uint4*)&knb[r][8] = *(uint4*)&kb[8];
        *(uint4*)&knb[r][16] = make_uint4(0u, 0u, 0u, 0u);   // pad k=16..23 -> finite zero
        #pragma unroll
        for (int d = 0; d < 16; ++d) vtb[d][r] = f2bs(vv[d]);
    }
    if (t < 16) {
        #pragma unroll
        for (int c = 0; c < 24; ++c) vtb[t][LL + c] = 0;     // pad rows 384..407
    }

    int w = t >> 6, l = t & 63;
    int lr = l & 15, q4 = l >> 4;
    *(uint2*)&ptile[w][lr][16 + q4 * 4] = make_uint2(0u, 0u);  // P cols 16..31 -> zero
    __syncthreads();

    bf16x8 zfrag = {0, 0, 0, 0, 0, 0, 0, 0};
    bf16x8 onesf;
    #pragma unroll
    for (int i = 0; i < 8; ++i) onesf[i] = (short)0x3F80;   // bf16 1.0

    int slot = 2 * w + z;
    int strips[3] = { slot, 15 - slot, 16 + slot };
    #pragma unroll
    for (int si = 0; si < 3; ++si) {
        int s = strips[si];
        int r0 = s * 16;
        bf16x8 afrag = *(const bf16x8*)&knb[r0 + lr][(q4 & 1) * 8];
        afrag = (q4 < 2) ? afrag : zfrag;
        float ccv[4];
        #pragma unroll
        for (int reg = 0; reg < 4; ++reg) ccv[reg] = cq[r0 + q4 * 4 + reg];

        f32x4 oacc = (f32x4){0.f, 0.f, 0.f, 0.f};
        f32x4 lacc = (f32x4){0.f, 0.f, 0.f, 0.f};

        for (int jt = 0; jt <= s; ++jt) {
            bf16x8 bfrag = *(const bf16x8*)&knb[jt * 16 + lr][q4 * 8];
            f32x4 sacc = __builtin_amdgcn_mfma_f32_16x16x32_bf16(
                afrag, bfrag, (f32x4){0.f, 0.f, 0.f, 0.f}, 0, 0, 0);
            int colg = jt * 16 + lr;
            #pragma unroll
            for (int reg = 0; reg < 4; ++reg) {
                int rowg = r0 + q4 * 4 + reg;
                float pe = __expf(fmaf(sacc[reg], ccv[reg], -ccv[reg]));
                pe = (colg < rowg) ? pe : 0.f;
                ptile[w][q4 * 4 + reg][lr] = f2bs(pe);
            }
            // wave-internal cross-lane LDS round trip: drain writes before read
            asm volatile("s_waitcnt lgkmcnt(0)" ::: "memory");
            bf16x8 pfrag = *(const bf16x8*)&ptile[w][lr][q4 * 8];
            bf16x8 vfrag = *(const bf16x8*)&vtb[lr][jt * 16 + q4 * 8];
            oacc = __builtin_amdgcn_mfma_f32_16x16x32_bf16(pfrag, vfrag, oacc, 0, 0, 0);
            lacc = __builtin_amdgcn_mfma_f32_16x16x32_bf16(pfrag, onesf, lacc, 0, 0, 0);
        }

        if (s == 0 && q4 == 0) {     // row 0: o = v_0
            lacc[0] = 1.0f;
            oacc[0] = bs2f(vtb[lr][0]);
        }
        unsigned short* ob = (unsigned short*)o + (size_t)(b * LL + r0) * DD + hh * 16 + lr;
        #pragma unroll
        for (int reg = 0; reg < 4; ++reg) {
            float ov = oacc[reg] / lacc[reg];
            ob[(size_t)(q4 * 4 + reg) * DD] = f2bs(ov);
        }
    }
}

// ---------------- final projection [64,49152] x [49152,128] ----------------
__global__ __launch_bounds__(256) void out_init_kernel(
    const float* __restrict__ bp, float* __restrict__ out)
{
    int t = blockIdx.x * 256 + threadIdx.x;   // 8192
    out[t] = bp[t & (COUT - 1)];
}

__global__ __launch_bounds__(256) void final_gemm_kernel(
    const float* __restrict__ xm, const float* __restrict__ Wp,
    float* __restrict__ out)
{
    int mq = blockIdx.x;        // 0..3 -> rows mq*16..+15
    int kc = blockIdx.y;        // 0..95 -> k chunk of 512
    __shared__ float xs[16][516];
    int k0 = kc * 512;
    #pragma unroll
    for (int p = 0; p < 8; ++p) {
        int id = threadIdx.x + p * 256;   // 0..2047 float4s
        int r = id >> 7;
        int c = (id & 127) << 2;
        *(float4*)&xs[r][c] = *(const float4*)(xm + (size_t)(mq * 16 + r) * KP + k0 + c);
    }
    __syncthreads();
    int n4 = (threadIdx.x & 31) << 2;
    int m2 = (threadIdx.x >> 5) << 1;    // 0,2,...,14
    float acc0[4] = {0.f, 0.f, 0.f, 0.f};
    float acc1[4] = {0.f, 0.f, 0.f, 0.f};
    for (int k = 0; k < 512; k += 4) {
        float4 xa = *(const float4*)&xs[m2][k];
        float4 xb = *(const float4*)&xs[m2 + 1][k];
        const float* wrow = Wp + (size_t)(k0 + k) * COUT + n4;
        float4 w0 = *(const float4*)(wrow);
        float4 w1 = *(const float4*)(wrow + COUT);
        float4 w2 = *(const float4*)(wrow + 2 * COUT);
        float4 w3 = *(const float4*)(wrow + 3 * COUT);
        float x0[4] = {xa.x, xa.y, xa.z, xa.w};
        float x1[4] = {xb.x, xb.y, xb.z, xb.w};
        float4 wv[4] = {w0, w1, w2, w3};
        #pragma unroll
        for (int kk = 0; kk < 4; ++kk) {
            acc0[0] = fmaf(x0[kk], wv[kk].x, acc0[0]);
            acc0[1] = fmaf(x0[kk], wv[kk].y, acc0[1]);
            acc0[2] = fmaf(x0[kk], wv[kk].z, acc0[2]);
            acc0[3] = fmaf(x0[kk], wv[kk].w, acc0[3]);
            acc1[0] = fmaf(x1[kk], wv[kk].x, acc1[0]);
            acc1[1] = fmaf(x1[kk], wv[kk].y, acc1[1]);
            acc1[2] = fmaf(x1[kk], wv[kk].z, acc1[2]);
            acc1[3] = fmaf(x1[kk], wv[kk].w, acc1[3]);
        }
    }
    int orow = mq * 16 + m2;
    #pragma unroll
    for (int c = 0; c < 4; ++c) {
        atomicAdd(&out[(size_t)orow * COUT + n4 + c], acc0[c]);
        atomicAdd(&out[(size_t)(orow + 1) * COUT + n4 + c], acc1[c]);
    }
}

// ---------------- launch ----------------
extern "C" void kernel_launch(void* const* d_in, const int* in_sizes, int n_in,
                              void* d_out, int out_size, void* d_ws, size_t ws_size,
                              hipStream_t stream)
{
    const int*   x_enc = (const int*)  d_in[0];
    const float* emb   = (const float*)d_in[1];
    const float* pos1  = (const float*)d_in[2];
    const float* pos2  = (const float*)d_in[3];
    const float* ln1_g = (const float*)d_in[4];
    const float* ln1_b = (const float*)d_in[5];
    const float* Wqk   = (const float*)d_in[6];
    const float* Wv    = (const float*)d_in[7];
    const float* Wo    = (const float*)d_in[8];
    const float* bo    = (const float*)d_in[9];
    const float* ln2_g = (const float*)d_in[10];
    const float* ln2_b = (const float*)d_in[11];
    const float* W1    = (const float*)d_in[12];
    const float* b1    = (const float*)d_in[13];
    const float* W2    = (const float*)d_in[14];
    const float* b2    = (const float*)d_in[15];
    const float* lnf_g = (const float*)d_in[16];
    const float* lnf_b = (const float*)d_in[17];
    const float* Wp    = (const float*)d_in[18];
    const float* bp    = (const float*)d_in[19];
    float* out = (float*)d_out;

    // workspace layout; SZ = 3,145,728 elements
    const size_t SZ = (size_t)MROWS * DD;
    float* ws_f = (float*)d_ws;
    float* x1 = ws_f;                    // fp32 [M,128]
    float* x2 = ws_f + SZ;               // fp32 [M,128]
    float* R  = ws_f + 2 * SZ;           // 2*SZ floats shared region
    float* qkv = R;                      // fp32 [M,256]  (lifetime: qkv-gemm..attn)
    __hip_bfloat16* hff = (__hip_bfloat16*)R;   // bf16 [M,512] (lifetime: ff1..ff2)
    float* hfin = R;                     // fp32 [M,128]  (final LN out)
    __hip_bfloat16* h_bf = (__hip_bfloat16*)(ws_f + 4 * SZ);  // bf16 [M,128]
    __hip_bfloat16* o_bf = h_bf + SZ;                          // bf16 [M,128]
    __hip_bfloat16* wqvT = o_bf + SZ;    // 6 * [256,128]  (Wqk^T rows 0..127, Wv^T rows 128..255)
    __hip_bfloat16* woT  = wqvT + 6 * 32768;         // 6 * [128,128]
    __hip_bfloat16* w1T  = woT  + 6 * 16384;         // 6 * [512,128]
    __hip_bfloat16* w2T  = w1T  + 6 * 65536;         // 6 * [128,512]

    // weight casts (transpose to [N,K] bf16)
    castT_kernel<<<dim3(4, 4, 6),  dim3(256), 0, stream>>>(Wqk, wqvT,         128, 128, 16384, 32768);
    castT_kernel<<<dim3(4, 4, 6),  dim3(256), 0, stream>>>(Wv,  wqvT + 16384, 128, 128, 16384, 32768);
    castT_kernel<<<dim3(4, 4, 6),  dim3(256), 0, stream>>>(Wo,  woT,          128, 128, 16384, 16384);
    castT_kernel<<<dim3(4, 16, 6), dim3(256), 0, stream>>>(W1,  w1T,          128, 512, 65536, 65536);
    castT_kernel<<<dim3(16, 4, 6), dim3(256), 0, stream>>>(W2,  w2T,          512, 128, 65536, 65536);

    embed_kernel<<<dim3(MROWS * 32 / 256), dim3(256), 0, stream>>>(x_enc, emb, pos1, pos2, x1, x2);

    for (int d = 0; d < DEPTH; ++d) {
        const float* l1g = ln1_g + d * DD;
        const float* l1b = ln1_b + d * DD;
        const float* bod = bo + d * DD;
        const float* l2g = ln2_g + d * DD;
        const float* l2b = ln2_b + d * DD;
        const float* b1d = b1 + d * FFD;
        const float* b2d = b2 + d * DD;
        const __hip_bfloat16* wqv_d = wqvT + (size_t)d * 32768;
        const __hip_bfloat16* wo_d  = woT  + (size_t)d * 16384;
        const __hip_bfloat16* w1_d  = w1T  + (size_t)d * 65536;
        const __hip_bfloat16* w2_d  = w2T  + (size_t)d * 65536;

        ln_kernel<<<dim3(MROWS / 4), dim3(256), 0, stream>>>(x2, l1g, l1b, h_bf);
        gemm_bf16<128, 256, false, false, false, false>
            <<<dim3(2, MROWS / 64), dim3(256), 0, stream>>>(h_bf, wqv_d, nullptr, nullptr, qkv);
        attn_kernel<<<dim3(BB * HH * 2), dim3(256), 0, stream>>>(qkv, o_bf);
        gemm_bf16<128, 128, true, true, false, false>
            <<<dim3(1, MROWS / 64), dim3(256), 0, stream>>>(o_bf, wo_d, bod, x1, x1);
        ln_kernel<<<dim3(MROWS / 4), dim3(256), 0, stream>>>(x1, l2g, l2b, h_bf);
        gemm_bf16<128, 512, true, false, true, true>
            <<<dim3(4, MROWS / 64), dim3(256), 0, stream>>>(h_bf, w1_d, b1d, nullptr, hff);
        gemm_bf16<512, 128, true, true, false, false>
            <<<dim3(1, MROWS / 64), dim3(256), 0, stream>>>(hff, w2_d, b2d, x2, x2);
    }

    avgln_kernel<<<dim3(MROWS / 4), dim3(256), 0, stream>>>(x1, x2, lnf_g, lnf_b, hfin);
    out_init_kernel<<<dim3(32), dim3(256), 0, stream>>>(bp, out);
    final_gemm_kernel<<<dim3(4, 96), dim3(256), 0, stream>>>(hfin, Wp, out);
}